// Round 3
// baseline (72.446 us; speedup 1.0000x reference)
//
#include <hip/hip_runtime.h>
#include <hip/hip_bf16.h>

#define D 8192
#define NPAIR 523776.0

typedef short short8 __attribute__((ext_vector_type(8)));
typedef float f32x4 __attribute__((ext_vector_type(4)));

__device__ __forceinline__ short8 cvt8(const float4 a, const float4 b) {
    union { short8 s; __hip_bfloat162 h[4]; } u;
    u.h[0] = __float22bfloat162_rn(make_float2(a.x, a.y));
    u.h[1] = __float22bfloat162_rn(make_float2(a.z, a.w));
    u.h[2] = __float22bfloat162_rn(make_float2(b.x, b.y));
    u.h[3] = __float22bfloat162_rn(make_float2(b.z, b.w));
    return u.s;
}

// 1024 blocks: bid = xcd(0..7) + 8*s, s in 0..127.
// m = xcd>>2 (matrix), xr = xcd&3.
// s < 112: off-diag tiles (28 pairs), chunk = 4*xr + s/28 (16 chunks of K=512)
// s >= 112: diag tiles (8), chunk = 2*xr + ((s-112)>>3) (8 chunks of K=1024)
__device__ __forceinline__ void decode_bid(int bid, int& m, int& ti, int& tj, int& k0, int& nsteps) {
    int x = bid & 7, s = bid >> 3;
    m = x >> 2;
    int xr = x & 3;
    if (s < 112) {
        int c = 4 * xr + s / 28;
        int tt = s % 28;
        int a = 0;
        while (tt >= 7 - a) { tt -= 7 - a; ++a; }
        ti = a; tj = a + 1 + tt;
        k0 = c * 512; nsteps = 16;
    } else {
        int r = s - 112;
        ti = tj = r & 7;
        int c = 2 * xr + (r >> 3);
        k0 = c * 1024; nsteps = 32;
    }
}
__device__ __forceinline__ int bid_off(int m, int tt, int c) {
    return (m * 4 + (c >> 2)) + (((c & 3) * 28 + tt) << 3);
}
__device__ __forceinline__ int bid_diag(int m, int dt, int c) {
    return (m * 4 + (c >> 1)) + ((112 + ((c & 1) << 3) + dt) << 3);
}

template<bool STORE>
__global__ __launch_bounds__(256)
void gram_kernel(const float* __restrict__ pred, const float* __restrict__ tgt,
                 float* __restrict__ out) {
    int m, ti, tj, k0, nsteps;
    decode_bid(blockIdx.x, m, ti, tj, k0, nsteps);
    const bool same = (ti == tj);
    const float* __restrict__ x = m ? tgt : pred;

    __shared__ short lsA[2][4096];   // [128 rows][32 k] bf16, XOR-swizzled 16B slots
    __shared__ short lsB[2][4096];

    const int tid = threadIdx.x;
    const int lane = tid & 63;
    const int wid = tid >> 6;
    const int wr = wid >> 1, wc = wid & 1;   // 4 waves: 2x2 grid of 64x64 wave tiles

    // staging: row = tid>>1 (0..127), half = tid&1 (k 0..15 or 16..31): 64B contiguous
    const int srow = tid >> 1, shalf = tid & 1;
    const float* __restrict__ gA = x + (size_t)(ti * 128 + srow) * D + k0 + shalf * 16;
    const float* __restrict__ gB = x + (size_t)(tj * 128 + srow) * D + k0 + shalf * 16;
    const int sw = (srow >> 1) & 3;
    const int wby0 = srow * 64 + (((2 * shalf)     ^ sw) << 4);
    const int wby1 = srow * 64 + (((2 * shalf + 1) ^ sw) << 4);

    // fragment read offsets (swizzle-consistent: 16-row strides don't change (row>>1)&3)
    const int rbA = (wr * 64 + (lane & 15)) * 64;
    const int rbB = (wc * 64 + (lane & 15)) * 64;
    const int kby = (((lane >> 4) ^ (((lane & 15) >> 1) & 3)) << 4);

    f32x4 zero = {0.f, 0.f, 0.f, 0.f};
    f32x4 acc[4][4];
#pragma unroll
    for (int mi = 0; mi < 4; ++mi)
#pragma unroll
        for (int ni = 0; ni < 4; ++ni) acc[mi][ni] = zero;

    float4 ra[4], rb[4];
    // prologue: load step0, write buf0, load step1
    {
        const float4* p = (const float4*)gA;
#pragma unroll
        for (int q = 0; q < 4; ++q) ra[q] = p[q];
        if (!same) {
            const float4* r = (const float4*)gB;
#pragma unroll
            for (int q = 0; q < 4; ++q) rb[q] = r[q];
        }
    }
    *(short8*)((char*)lsA[0] + wby0) = cvt8(ra[0], ra[1]);
    *(short8*)((char*)lsA[0] + wby1) = cvt8(ra[2], ra[3]);
    if (!same) {
        *(short8*)((char*)lsB[0] + wby0) = cvt8(rb[0], rb[1]);
        *(short8*)((char*)lsB[0] + wby1) = cvt8(rb[2], rb[3]);
    }
    {
        const float4* p = (const float4*)(gA + 32);
#pragma unroll
        for (int q = 0; q < 4; ++q) ra[q] = p[q];
        if (!same) {
            const float4* r = (const float4*)(gB + 32);
#pragma unroll
            for (int q = 0; q < 4; ++q) rb[q] = r[q];
        }
    }
    asm volatile("s_waitcnt lgkmcnt(0)" ::: "memory");
    __builtin_amdgcn_s_barrier();

    for (int step = 0; step < nsteps; ++step) {
        const int cur = step & 1;
        const short* __restrict__ bufA = lsA[cur];
        const short* __restrict__ bufB = same ? lsA[cur] : lsB[cur];

        // compute first (reads only depend on the barrier), stage-write late (T14)
        __builtin_amdgcn_s_setprio(1);
        short8 bf[4];
#pragma unroll
        for (int ni = 0; ni < 4; ++ni)
            bf[ni] = *(const short8*)((const char*)bufB + (rbB + ni * 1024 + kby));
#pragma unroll
        for (int mi = 0; mi < 4; ++mi) {
            short8 af = *(const short8*)((const char*)bufA + (rbA + mi * 1024 + kby));
#pragma unroll
            for (int ni = 0; ni < 4; ++ni)
                acc[mi][ni] = __builtin_amdgcn_mfma_f32_16x16x32_bf16(af, bf[ni], acc[mi][ni], 0, 0, 0);
        }
        __builtin_amdgcn_s_setprio(0);

        if (step + 1 < nsteps) {
            const int nxt = cur ^ 1;
            *(short8*)((char*)lsA[nxt] + wby0) = cvt8(ra[0], ra[1]);
            *(short8*)((char*)lsA[nxt] + wby1) = cvt8(ra[2], ra[3]);
            if (!same) {
                *(short8*)((char*)lsB[nxt] + wby0) = cvt8(rb[0], rb[1]);
                *(short8*)((char*)lsB[nxt] + wby1) = cvt8(rb[2], rb[3]);
            }
            if (step + 2 < nsteps) {   // prefetch; stays in flight across the barrier
                const float4* p = (const float4*)(gA + (step + 2) * 32);
#pragma unroll
                for (int q = 0; q < 4; ++q) ra[q] = p[q];
                if (!same) {
                    const float4* r = (const float4*)(gB + (step + 2) * 32);
#pragma unroll
                    for (int q = 0; q < 4; ++q) rb[q] = r[q];
                }
            }
        }
        asm volatile("s_waitcnt lgkmcnt(0)" ::: "memory");
        __builtin_amdgcn_s_barrier();
    }

    if (STORE) {
        float* __restrict__ dst = out + (size_t)blockIdx.x * 16384;
#pragma unroll
        for (int mi = 0; mi < 4; ++mi)
#pragma unroll
            for (int ni = 0; ni < 4; ++ni)
#pragma unroll
                for (int r = 0; r < 4; ++r) {
                    int li = wr * 64 + mi * 16 + (lane >> 4) * 4 + r;
                    int lj = wc * 64 + ni * 16 + (lane & 15);
                    dst[li * 128 + lj] = acc[mi][ni][r];
                }
    } else {
        float* __restrict__ g = out + (size_t)m * (1024 * 1024);
#pragma unroll
        for (int mi = 0; mi < 4; ++mi)
#pragma unroll
            for (int ni = 0; ni < 4; ++ni)
#pragma unroll
                for (int r = 0; r < 4; ++r) {
                    int gi = ti * 128 + wr * 64 + mi * 16 + (lane >> 4) * 4 + r;
                    int gj = tj * 128 + wc * 64 + ni * 16 + (lane & 15);
                    atomicAdd(&g[gi * 1024 + gj], acc[mi][ni][r]);
                }
    }
}

__global__ __launch_bounds__(256)
void norms_kernel(const float* __restrict__ part, float* __restrict__ norms) {
    int id = blockIdx.x * 256 + threadIdx.x;   // 0..2047: m = id>>10, i = id&1023
    int m = id >> 10, i = id & 1023;
    int dt = i >> 7, li = i & 127;
    float s = 0.f;
#pragma unroll
    for (int c = 0; c < 8; ++c)
        s += part[(size_t)bid_diag(m, dt, c) * 16384 + li * 129];
    norms[id] = s;
}

__global__ __launch_bounds__(256)
void loss_store_kernel(const float* __restrict__ part, const float* __restrict__ norms,
                       float* __restrict__ partial) {
    const int tid = threadIdx.x;
    const int base = blockIdx.x * 256 + tid;
    float local = 0.f;
#pragma unroll
    for (int s = 0; s < 4; ++s) {
        int lin = base + s * 262144;
        int i = lin >> 10, j = lin & 1023;
        if (j > i) {
            int ti = i >> 7, tj = j >> 7;
            int el = (i & 127) * 128 + (j & 127);
            float gp = 0.f, gt = 0.f;
            if (ti == tj) {
#pragma unroll
                for (int c = 0; c < 8; ++c) {
                    gp += part[(size_t)bid_diag(0, ti, c) * 16384 + el];
                    gt += part[(size_t)bid_diag(1, ti, c) * 16384 + el];
                }
            } else {
                int tt = 7 * ti - (ti * (ti - 1)) / 2 + (tj - ti - 1);
#pragma unroll
                for (int c = 0; c < 16; ++c) {
                    gp += part[(size_t)bid_off(0, tt, c) * 16384 + el];
                    gt += part[(size_t)bid_off(1, tt, c) * 16384 + el];
                }
            }
            float dp = norms[i] + norms[j] - 2.f * gp;
            float dt_ = norms[1024 + i] + norms[1024 + j] - 2.f * gt;
            float c2 = sqrtf(fmaxf(dp, 0.f)) - sqrtf(fmaxf(dt_, 0.f));
            local += c2 * c2;
        }
    }
#pragma unroll
    for (int off = 32; off > 0; off >>= 1) local += __shfl_down(local, off);
    __shared__ float wsum[4];
    if ((tid & 63) == 0) wsum[tid >> 6] = local;
    __syncthreads();
    if (tid == 0) partial[blockIdx.x] = wsum[0] + wsum[1] + wsum[2] + wsum[3];
}

// fallback loss (atomic path): reads dense gram[2][1024][1024]
__global__ __launch_bounds__(256)
void loss_atomic_kernel(const float* __restrict__ gram, float* __restrict__ partial) {
    const float* __restrict__ gP = gram;
    const float* __restrict__ gT = gram + 1024 * 1024;
    const int tid = threadIdx.x;
    const int base = blockIdx.x * 256 + tid;
    float local = 0.f;
#pragma unroll
    for (int s = 0; s < 4; ++s) {
        int lin = base + s * 262144;
        int i = lin >> 10, j = lin & 1023;
        if (j > i) {
            float dp = gP[i * 1024 + i] + gP[j * 1024 + j] - 2.f * gP[lin];
            float dt = gT[i * 1024 + i] + gT[j * 1024 + j] - 2.f * gT[lin];
            float c = sqrtf(fmaxf(dp, 0.f)) - sqrtf(fmaxf(dt, 0.f));
            local += c * c;
        }
    }
#pragma unroll
    for (int off = 32; off > 0; off >>= 1) local += __shfl_down(local, off);
    __shared__ float wsum[4];
    if ((tid & 63) == 0) wsum[tid >> 6] = local;
    __syncthreads();
    if (tid == 0) partial[blockIdx.x] = wsum[0] + wsum[1] + wsum[2] + wsum[3];
}

__global__ __launch_bounds__(256)
void finalize_kernel(const float* __restrict__ partial, float* __restrict__ out) {
    const int tid = threadIdx.x;
    double local = 0.0;
#pragma unroll
    for (int k = 0; k < 4; ++k) local += (double)partial[tid + k * 256];
#pragma unroll
    for (int off = 32; off > 0; off >>= 1) local += __shfl_down(local, off);
    __shared__ double wsum[4];
    if ((tid & 63) == 0) wsum[tid >> 6] = local;
    __syncthreads();
    if (tid == 0) out[0] = (float)((wsum[0] + wsum[1] + wsum[2] + wsum[3]) / NPAIR);
}

extern "C" void kernel_launch(void* const* d_in, const int* in_sizes, int n_in,
                              void* d_out, int out_size, void* d_ws, size_t ws_size,
                              hipStream_t stream) {
    const float* pred = (const float*)d_in[0];
    const float* tgt  = (const float*)d_in[1];
    float* ws = (float*)d_ws;
    const size_t need = (size_t)1024 * 16384 * 4 + (2048 + 1024) * 4;
    if (ws_size >= need) {
        float* part    = ws;                           // 1024 x 16384 f32 = 67 MB
        float* norms   = ws + (size_t)1024 * 16384;    // 2048 f32
        float* partial = norms + 2048;                 // 1024 f32
        gram_kernel<true><<<1024, 256, 0, stream>>>(pred, tgt, part);
        norms_kernel<<<8, 256, 0, stream>>>(part, norms);
        loss_store_kernel<<<1024, 256, 0, stream>>>(part, norms, partial);
        finalize_kernel<<<1, 256, 0, stream>>>(partial, (float*)d_out);
    } else {
        float* gram    = ws;                           // 2 x 1024 x 1024 f32 = 8 MB
        float* partial = ws + (size_t)2 * 1024 * 1024;
        hipMemsetAsync(gram, 0, (size_t)2 * 1024 * 1024 * sizeof(float), stream);
        gram_kernel<false><<<1024, 256, 0, stream>>>(pred, tgt, gram);
        loss_atomic_kernel<<<1024, 256, 0, stream>>>(gram, partial);
        finalize_kernel<<<1, 256, 0, stream>>>(partial, (float*)d_out);
    }
}